// Round 9
// baseline (203.123 us; speedup 1.0000x reference)
//
#include <hip/hip_runtime.h>
#include <math.h>

#define RR 1024
#define BB 16
#define DD 1024
#define K_ACTIVE 20

// clang native vector type: __builtin_nontemporal_store rejects HIP's
// float4 (HIP_vector_type class). Same 16B layout.
typedef float f32x4 __attribute__((ext_vector_type(4)));

// ---------------------------------------------------------------------------
// Kernel 1: per (r,b) pair compute dot(H[r,b,:], w) and sumsq(msg[r,b,:]),
// then adj[b,r] = s - theta[r] - refr[b,r] - 0.5*(0.9*fb[b,r] + 0.1*||msg||),
// and zero-fill Hs[pair,:].
// Round-8 post-mortem: LDS-w + __syncthreads was a scheduling fence
// (s_waitcnt vmcnt(0) before s_barrier) -> loads serialized, VGPR stuck at
// 32, 3.2 TB/s. This version: NO LDS, NO barrier. Zero-stores issue first
// (no dependencies), then all 12 float4 loads batched into register arrays
// (w is 4 KB, L1-broadcast-hot), then compute. Copy-ubench structure.
// ---------------------------------------------------------------------------
__global__ __launch_bounds__(256, 4) void score_kernel(
    const float* __restrict__ H, const float* __restrict__ msg,
    const float* __restrict__ w, const float* __restrict__ theta,
    const float* __restrict__ refr, const float* __restrict__ fb,
    float* __restrict__ adj_out, float* __restrict__ Hs)
{
    const int wave = threadIdx.x >> 6;
    const int lane = threadIdx.x & 63;
    const int pair = blockIdx.x * 4 + wave;   // pair = r*BB + b (row-major [R,B])
    const int r = pair >> 4;
    const int b = pair & 15;

    const float4* H4 = (const float4*)(H + (size_t)pair * DD);
    const float4* M4 = (const float4*)(msg + (size_t)pair * DD);
    const float4* W4 = (const float4*)w;
    f32x4* Z4 = (f32x4*)(Hs + (size_t)pair * DD);

    // Fire-and-forget zero stores FIRST (depend on nothing; nontemporal).
    const f32x4 zero4 = (f32x4){0.f, 0.f, 0.f, 0.f};
#pragma unroll
    for (int k = 0; k < 4; ++k)
        __builtin_nontemporal_store(zero4, &Z4[lane + 64 * k]);

    // Batch ALL loads into register arrays (12 x 16B in flight per lane).
    float4 h[4], m[4], ww[4];
#pragma unroll
    for (int k = 0; k < 4; ++k) {
        const int i = lane + 64 * k;          // 256 float4 = 1024 floats
        h[k]  = H4[i];
        m[k]  = M4[i];
        ww[k] = W4[i];                        // 4 KB total, L1/L2-hot broadcast
    }

    float dot = 0.f, ss = 0.f;
#pragma unroll
    for (int k = 0; k < 4; ++k) {
        dot += h[k].x * ww[k].x + h[k].y * ww[k].y + h[k].z * ww[k].z + h[k].w * ww[k].w;
        ss  += m[k].x * m[k].x + m[k].y * m[k].y + m[k].z * m[k].z + m[k].w * m[k].w;
    }
    // wave-64 reduction
#pragma unroll
    for (int off = 32; off > 0; off >>= 1) {
        dot += __shfl_down(dot, off);
        ss  += __shfl_down(ss, off);
    }
    if (lane == 0) {
        const float fb_mag = sqrtf(ss);
        const float fb_new = 0.9f * fb[b * RR + r] + 0.1f * fb_mag;
        const float a = dot - theta[r] - refr[b * RR + r] - 0.5f * fb_new;
        adj_out[b * RR + r] = a;
    }
}

// ---------------------------------------------------------------------------
// Kernel 2 (fused NMS + gate): one block per batch, 256 threads.
//   Wave 0: greedy hex NMS, register-resident (depth-4 argmax tree with
//     tie -> lower index, 6-step shfl_xor butterfly, bitmask suppression,
//     neighbors from an LDS copy of nbrs). Writes hard[b,:]; deposits the
//     selected region list + count into LDS.
//   Then ALL 256 threads copy the <=20 selected rows H[r,b,:] -> Hs[r,b,:]
//     (one float4 per thread per row). Zeros pre-written by score_kernel.
// ---------------------------------------------------------------------------
__global__ __launch_bounds__(256) void nms_gate_kernel(
    const float* __restrict__ adj, const int* __restrict__ nbrs,
    const float* __restrict__ H,
    float* __restrict__ hard, float* __restrict__ Hs)
{
    __shared__ int nb_lds[RR * 6];            // 24 KiB
    __shared__ int sel_r[K_ACTIVE];
    __shared__ int nsel_lds;

    const int b = blockIdx.x;
    const int tid = threadIdx.x;
    const int lane = tid & 63;
    const int wave = tid >> 6;

    // Preload neighbor table: 6144 ints = 1536 int4, 6 int4 per thread.
    {
        const int4* nb4 = (const int4*)nbrs;
        int4* nl4 = (int4*)nb_lds;
#pragma unroll
        for (int j = 0; j < 6; ++j)
            nl4[tid + 256 * j] = nb4[tid + 256 * j];
    }
    __syncthreads();

    if (wave == 0) {
        // Load this batch's adj row into registers (coalesced, wave 0 only).
        float v[16];
#pragma unroll
        for (int j = 0; j < 16; ++j)
            v[j] = adj[b * RR + lane + 64 * j];

        unsigned int sel = 0u;    // bit j: region lane+64j selected
        unsigned int dead = 0u;   // bit j: region lane+64j suppressed/selected
        int nsel = 0;

        for (int it = 0; it < K_ACTIVE; ++it) {
            // per-lane argmax over alive slots (tree; tie keeps lower j)
            float tv[16]; int ti[16];
#pragma unroll
            for (int j = 0; j < 16; ++j) {
                tv[j] = ((dead >> j) & 1u) ? -INFINITY : v[j];
                ti[j] = lane + 64 * j;
            }
#pragma unroll
            for (int s = 8; s >= 1; s >>= 1) {
#pragma unroll
                for (int j = 0; j < 8; ++j) {
                    if (j < s) {
                        if (tv[j + s] > tv[j]) { tv[j] = tv[j + s]; ti[j] = ti[j + s]; }
                    }
                }
            }
            float m = tv[0];
            int mi = ti[0];

            // wave-64 butterfly argmax (tie -> lowest index)
#pragma unroll
            for (int off = 32; off > 0; off >>= 1) {
                const float ov = __shfl_xor(m, off);
                const int   oi = __shfl_xor(mi, off);
                if (ov > m || (ov == m && oi < mi)) { m = ov; mi = oi; }
            }
            // all lanes agree on (m, mi) now

            if (m == -INFINITY) break;   // parity with reference exhaustion

            if (lane == 0) sel_r[nsel] = mi;
            nsel++;

            // suppress mi and its 6 neighbors (bitmask updates)
            int sup[7];
            sup[0] = mi;
            const int base = mi * 6;
#pragma unroll
            for (int k = 0; k < 6; ++k) sup[k + 1] = nb_lds[base + k];  // broadcast

            sel |= ((mi & 63) == lane) ? (1u << (mi >> 6)) : 0u;
#pragma unroll
            for (int k = 0; k < 7; ++k)
                dead |= ((sup[k] & 63) == lane) ? (1u << (sup[k] >> 6)) : 0u;
        }

        if (lane == 0) nsel_lds = nsel;

        // hard output for this batch
#pragma unroll
        for (int j = 0; j < 16; ++j)
            hard[b * RR + lane + 64 * j] = ((sel >> j) & 1u) ? 1.0f : 0.0f;
    }
    __syncthreads();

    // All 256 threads: copy selected rows H[r,b,:] -> Hs[r,b,:] (4 KB each,
    // one float4 per thread per row; iterations' loads are independent).
    const int nsel = nsel_lds;
    for (int s = 0; s < nsel; ++s) {
        const int r = sel_r[s];
        const size_t off = ((size_t)r * BB + b) * DD;
        ((float4*)(Hs + off))[tid] = ((const float4*)(H + off))[tid];
    }
}

extern "C" void kernel_launch(void* const* d_in, const int* in_sizes, int n_in,
                              void* d_out, int out_size, void* d_ws, size_t ws_size,
                              hipStream_t stream) {
    const float* H     = (const float*)d_in[0];   // [R,B,D]
    const float* msg   = (const float*)d_in[1];   // [R,B,D]
    const float* w     = (const float*)d_in[2];   // [D]
    const float* theta = (const float*)d_in[3];   // [R]
    const float* refr  = (const float*)d_in[4];   // [B,R]
    const float* fb    = (const float*)d_in[5];   // [B,R]
    const int*   nbrs  = (const int*)d_in[6];     // [R,6]

    float* out  = (float*)d_out;
    float* Hs   = out;                                   // [R,B,D]
    float* hard = out + (size_t)RR * BB * DD;            // [B,R]
    float* adj  = hard + (size_t)BB * RR;                // [B,R]

    score_kernel<<<RR * BB / 4, 256, 0, stream>>>(H, msg, w, theta, refr, fb, adj, Hs);
    nms_gate_kernel<<<BB, 256, 0, stream>>>(adj, nbrs, H, hard, Hs);
}

// Round 14
// 198.669 us; speedup vs baseline: 1.0224x; 1.0224x over previous
//
#include <hip/hip_runtime.h>
#include <math.h>

#define RR 1024
#define BB 16
#define DD 1024
#define K_ACTIVE 20

// clang native vector type for __builtin_nontemporal_store (rejects HIP float4).
typedef float f32x4 __attribute__((ext_vector_type(4)));

// ---------------------------------------------------------------------------
// Kernel 1: PURE READER. Per (r,b) pair: dot(H[r,b,:], w), sumsq(msg[r,b,:]),
// adj[b,r] = s - theta[r] - refr[b,r] - 0.5*(0.9*fb[b,r] + 0.1*||msg||).
// Round-9 post-mortem: every variant that mixed the 64 MB Hs write into this
// kernel pinned at ~60 us / 2.2 TB/s regardless of scheduling structure.
// This version writes nothing but adj (64 KB) - clean read stream.
// ---------------------------------------------------------------------------
__global__ __launch_bounds__(256, 4) void score_kernel(
    const float* __restrict__ H, const float* __restrict__ msg,
    const float* __restrict__ w, const float* __restrict__ theta,
    const float* __restrict__ refr, const float* __restrict__ fb,
    float* __restrict__ adj_out)
{
    const int wave = threadIdx.x >> 6;
    const int lane = threadIdx.x & 63;
    const int pair = blockIdx.x * 4 + wave;   // pair = r*BB + b (row-major [R,B])
    const int r = pair >> 4;
    const int b = pair & 15;

    const float4* H4 = (const float4*)(H + (size_t)pair * DD);
    const float4* M4 = (const float4*)(msg + (size_t)pair * DD);
    const float4* W4 = (const float4*)w;

    // Batch all loads into register arrays (12 x 16B in flight per lane).
    float4 h[4], m[4], ww[4];
#pragma unroll
    for (int k = 0; k < 4; ++k) {
        const int i = lane + 64 * k;          // 256 float4 = 1024 floats
        h[k]  = H4[i];
        m[k]  = M4[i];
        ww[k] = W4[i];                        // 4 KB total, L1/L2-hot broadcast
    }

    float dot = 0.f, ss = 0.f;
#pragma unroll
    for (int k = 0; k < 4; ++k) {
        dot += h[k].x * ww[k].x + h[k].y * ww[k].y + h[k].z * ww[k].z + h[k].w * ww[k].w;
        ss  += m[k].x * m[k].x + m[k].y * m[k].y + m[k].z * m[k].z + m[k].w * m[k].w;
    }
    // wave-64 reduction
#pragma unroll
    for (int off = 32; off > 0; off >>= 1) {
        dot += __shfl_down(dot, off);
        ss  += __shfl_down(ss, off);
    }
    if (lane == 0) {
        const float fb_mag = sqrtf(ss);
        const float fb_new = 0.9f * fb[b * RR + r] + 0.1f * fb_mag;
        const float a = dot - theta[r] - refr[b * RR + r] - 0.5f * fb_new;
        adj_out[b * RR + r] = a;
    }
}

// ---------------------------------------------------------------------------
// Kernel 2: greedy hex NMS, ONE WAVE per batch, fully register-resident.
// Each lane owns 16 regions. Per iteration: depth-4 register argmax tree
// (tie -> lower j = lower idx), 6-step shfl_xor butterfly (tie -> lower
// lane), bitmask suppression, neighbors from LDS copy of nbrs. Writes hard.
// (Logic verified across rounds 3/8/9.)
// ---------------------------------------------------------------------------
__global__ __launch_bounds__(64) void nms_kernel(
    const float* __restrict__ adj, const int* __restrict__ nbrs,
    float* __restrict__ hard)
{
    __shared__ int nb_lds[RR * 6];            // 24 KiB

    const int b = blockIdx.x;
    const int lane = threadIdx.x;             // 0..63, single wave

    // Preload neighbor table: 6144 ints = 1536 int4, 24 int4 per lane.
    {
        const int4* nb4 = (const int4*)nbrs;
        int4* nl4 = (int4*)nb_lds;
#pragma unroll
        for (int j = 0; j < 24; ++j)
            nl4[lane + 64 * j] = nb4[lane + 64 * j];
    }

    // Load this batch's adj row into registers (coalesced).
    float v[16];
#pragma unroll
    for (int j = 0; j < 16; ++j)
        v[j] = adj[b * RR + lane + 64 * j];

    __syncthreads();   // single wave: cheap; ensures LDS preload visible

    unsigned int sel = 0u;    // bit j: region lane+64j selected
    unsigned int dead = 0u;   // bit j: region lane+64j suppressed/selected

    for (int it = 0; it < K_ACTIVE; ++it) {
        float tv[16]; int ti[16];
#pragma unroll
        for (int j = 0; j < 16; ++j) {
            tv[j] = ((dead >> j) & 1u) ? -INFINITY : v[j];
            ti[j] = lane + 64 * j;
        }
#pragma unroll
        for (int s = 8; s >= 1; s >>= 1) {
#pragma unroll
            for (int j = 0; j < 8; ++j) {
                if (j < s) {
                    if (tv[j + s] > tv[j]) { tv[j] = tv[j + s]; ti[j] = ti[j + s]; }
                }
            }
        }
        float m = tv[0];
        int mi = ti[0];

#pragma unroll
        for (int off = 32; off > 0; off >>= 1) {
            const float ov = __shfl_xor(m, off);
            const int   oi = __shfl_xor(mi, off);
            if (ov > m || (ov == m && oi < mi)) { m = ov; mi = oi; }
        }

        if (m == -INFINITY) break;   // parity with reference exhaustion

        int sup[7];
        sup[0] = mi;
        const int base = mi * 6;
#pragma unroll
        for (int k = 0; k < 6; ++k) sup[k + 1] = nb_lds[base + k];  // broadcast

        sel |= ((mi & 63) == lane) ? (1u << (mi >> 6)) : 0u;
#pragma unroll
        for (int k = 0; k < 7; ++k)
            dead |= ((sup[k] & 63) == lane) ? (1u << (sup[k] >> 6)) : 0u;
    }

#pragma unroll
    for (int j = 0; j < 16; ++j)
        hard[b * RR + lane + 64 * j] = ((sel >> j) & 1u) ? 1.0f : 0.0f;
}

// ---------------------------------------------------------------------------
// Kernel 3: PURE WRITER. Hs[r,b,:] = hard[b,r] ? H[r,b,:] : 0.
// Nontemporal stores: the 64 MB zero stream must not evict H/msg from L3
// (keeps next iteration's score reads L3-hot). Gated-off rows write zeros
// without reading H, so only ~2% of H is re-read. Grid-stride, 8 pairs/block.
// ---------------------------------------------------------------------------
__global__ __launch_bounds__(256) void gate_kernel(
    const float* __restrict__ H, const float* __restrict__ hard,
    float* __restrict__ Hs)
{
    const int tid = threadIdx.x;
    const f32x4 zero4 = (f32x4){0.f, 0.f, 0.f, 0.f};
    for (int pair = blockIdx.x; pair < RR * BB; pair += gridDim.x) {
        const int r = pair >> 4;
        const int b = pair & 15;
        const float g = hard[b * RR + r];    // broadcast scalar, L2-hot
        f32x4* out4 = (f32x4*)(Hs + (size_t)pair * DD);
        if (g != 0.0f) {
            const float4* H4 = (const float4*)(H + (size_t)pair * DD);
            const float4 t = H4[tid];
            __builtin_nontemporal_store((f32x4){t.x, t.y, t.z, t.w}, &out4[tid]);
        } else {
            __builtin_nontemporal_store(zero4, &out4[tid]);
        }
    }
}

extern "C" void kernel_launch(void* const* d_in, const int* in_sizes, int n_in,
                              void* d_out, int out_size, void* d_ws, size_t ws_size,
                              hipStream_t stream) {
    const float* H     = (const float*)d_in[0];   // [R,B,D]
    const float* msg   = (const float*)d_in[1];   // [R,B,D]
    const float* w     = (const float*)d_in[2];   // [D]
    const float* theta = (const float*)d_in[3];   // [R]
    const float* refr  = (const float*)d_in[4];   // [B,R]
    const float* fb    = (const float*)d_in[5];   // [B,R]
    const int*   nbrs  = (const int*)d_in[6];     // [R,6]

    float* out  = (float*)d_out;
    float* Hs   = out;                                   // [R,B,D]
    float* hard = out + (size_t)RR * BB * DD;            // [B,R]
    float* adj  = hard + (size_t)BB * RR;                // [B,R]

    score_kernel<<<RR * BB / 4, 256, 0, stream>>>(H, msg, w, theta, refr, fb, adj);
    nms_kernel<<<BB, 64, 0, stream>>>(adj, nbrs, hard);
    gate_kernel<<<2048, 256, 0, stream>>>(H, hard, Hs);
}